// Round 4
// baseline (27.356 us; speedup 1.0000x reference)
//
#include <hip/hip_runtime.h>

// OversizeConv2d via MFMA: Z = A_h * X * A_w^T + hb*s_w[ow] + wb per (b,c) image.
// Pass A: P = X * Aw^T, X A-fragments loaded DIRECTLY from global (per-lane f32->bf16).
// Pass B (operand-swapped): Z^T = PT * Ah^T -> j-contiguous f32x4 stores.
// Block = one channel, 2 images; grid 2048; LDS ~30KB -> 5 blocks/CU.

#define STRB 72   // bf16 LDS row stride: 144 B

typedef short  bfrag  __attribute__((ext_vector_type(8)));   // 8 bf16 = 4 VGPR
typedef float  f32x4  __attribute__((ext_vector_type(4)));
typedef unsigned short us4 __attribute__((ext_vector_type(4)));

__device__ __forceinline__ unsigned short f2bf(float f) {
    unsigned u = __builtin_bit_cast(unsigned, f);
    u += 0x7fffu + ((u >> 16) & 1u);          // round-to-nearest-even
    return (unsigned short)(u >> 16);
}

// LDS-visibility barrier WITHOUT vmcnt drain
__device__ __forceinline__ void lds_barrier() {
    asm volatile("s_waitcnt lgkmcnt(0)" ::: "memory");
    __builtin_amdgcn_s_barrier();
}

__global__ __launch_bounds__(256, 5)
void oversize_conv_mfma2(const float* __restrict__ x,
                         const float* __restrict__ hwt,   // (128,1,13,1)
                         const float* __restrict__ wwt,   // (128,1,1,13)
                         const float* __restrict__ hb,
                         const float* __restrict__ wb,
                         float* __restrict__ out)
{
    __shared__ __align__(16) unsigned short Aw[64 * STRB];  // Aw[ow][iw] (B^T, pass A)
    __shared__ __align__(16) unsigned short Ah[64 * STRB];  // Ah[oh][ih] (B^T, pass B swapped)
    __shared__ __align__(16) unsigned short PT[64 * STRB];  // P^T [ow][h]
    __shared__ float hk[128], wk[128], swp[256];
    __shared__ __align__(16) float sw[64];

    const int tid = threadIdx.x;
    const int c   = blockIdx.x & 127;          // channel
    const int bb  = (blockIdx.x >> 7) * 2;     // first batch of the pair
    const size_t img0      = ((size_t)bb * 128 + c) * 4096;
    const size_t imgStride = (size_t)128 * 4096;

    const int wv = tid >> 6, lane = tid & 63;
    const int r = lane & 15, gq = lane >> 4;

    // ---- issue image-0 loads immediately: lane needs X[16wv+r][8gq..+7] and [32+8gq..+7]
    const float4* xrow0 = (const float4*)(x + img0 + (size_t)(16 * wv + r) * 64);
    float4 xa0 = xrow0[2 * gq];
    float4 xa1 = xrow0[2 * gq + 1];
    float4 xa2 = xrow0[8 + 2 * gq];
    float4 xa3 = xrow0[9 + 2 * gq];

    // ---- interpolate 13 -> 127 taps (align_corners linear)
    if (tid < 127) {
        const float scale = 12.0f / 126.0f;
        float pos = (float)tid * scale;
        int   lo  = (int)pos;
        float fr  = pos - (float)lo;
        int   hi  = (lo + 1 < 12) ? lo + 1 : 12;
        hk[tid] = hwt[c * 13 + lo] * (1.0f - fr) + hwt[c * 13 + hi] * fr;
        wk[tid] = wwt[c * 13 + lo] * (1.0f - fr) + wwt[c * 13 + hi] * fr;
    }
    lds_barrier();

    // ---- build Toeplitz factors (bf16), once per block
    {
        const int row = tid >> 2;            // 0..63
        const int cb  = (tid & 3) * 16;
        #pragma unroll
        for (int q = 0; q < 4; ++q) {
            us4 vh, vw;
            #pragma unroll
            for (int j = 0; j < 4; ++j) {
                int col = cb + q * 4 + j;
                vh[j] = f2bf(hk[col - row + 63]);
                vw[j] = f2bf(wk[col - row + 63]);
            }
            *(us4*)&Ah[row * STRB + cb + q * 4] = vh;
            *(us4*)&Aw[row * STRB + cb + q * 4] = vw;
        }
    }
    // ---- s_w partials: 4 threads per ow, 16 taps each
    {
        const int ow = tid >> 2, q = tid & 3;
        float s = 0.f;
        #pragma unroll
        for (int i = 0; i < 16; ++i) s += wk[(q * 16 + i) - ow + 63];
        swp[tid] = s;
    }
    lds_barrier();
    if (tid < 64)
        sw[tid] = swp[4 * tid] + swp[4 * tid + 1] + swp[4 * tid + 2] + swp[4 * tid + 3];
    // (sw becomes visible to all waves at the next lds_barrier, before first use)

    const float hbc = hb[c], wbc = wb[c];

    #pragma unroll
    for (int i = 0; i < 2; ++i) {
        // ---- convert current image regs -> A fragments
        bfrag a0, a1;
        a0[0] = (short)f2bf(xa0.x); a0[1] = (short)f2bf(xa0.y);
        a0[2] = (short)f2bf(xa0.z); a0[3] = (short)f2bf(xa0.w);
        a0[4] = (short)f2bf(xa1.x); a0[5] = (short)f2bf(xa1.y);
        a0[6] = (short)f2bf(xa1.z); a0[7] = (short)f2bf(xa1.w);
        a1[0] = (short)f2bf(xa2.x); a1[1] = (short)f2bf(xa2.y);
        a1[2] = (short)f2bf(xa2.z); a1[3] = (short)f2bf(xa2.w);
        a1[4] = (short)f2bf(xa3.x); a1[5] = (short)f2bf(xa3.y);
        a1[6] = (short)f2bf(xa3.z); a1[7] = (short)f2bf(xa3.w);

        // ---- prefetch next image into the same regs (latency hides under A+B)
        if (i == 0) {
            const float4* xr = (const float4*)(x + img0 + imgStride + (size_t)(16 * wv + r) * 64);
            xa0 = xr[2 * gq];
            xa1 = xr[2 * gq + 1];
            xa2 = xr[8 + 2 * gq];
            xa3 = xr[9 + 2 * gq];
        }

        // ---- pass A: P = X * Aw^T  (wave wv owns P rows 16wv..16wv+15)
        f32x4 acc[4] = {};
        #pragma unroll
        for (int nt = 0; nt < 4; ++nt) {
            bfrag b0 = *(const bfrag*)&Aw[(nt * 16 + r) * STRB + gq * 8];
            bfrag b1 = *(const bfrag*)&Aw[(nt * 16 + r) * STRB + 32 + gq * 8];
            acc[nt] = __builtin_amdgcn_mfma_f32_16x16x32_bf16(a0, b0, acc[nt], 0, 0, 0);
            acc[nt] = __builtin_amdgcn_mfma_f32_16x16x32_bf16(a1, b1, acc[nt], 0, 0, 0);
        }
        // ---- write P transposed: PT[ow=16nt+r][h=16wv+4gq+j]
        #pragma unroll
        for (int nt = 0; nt < 4; ++nt) {
            us4 p;
            p[0] = f2bf(acc[nt][0]); p[1] = f2bf(acc[nt][1]);
            p[2] = f2bf(acc[nt][2]); p[3] = f2bf(acc[nt][3]);
            *(us4*)&PT[(nt * 16 + r) * STRB + wv * 16 + gq * 4] = p;
        }
        lds_barrier();   // PT visible (and sw on first pass)

        // ---- pass B (swapped): Z^T = PT * Ah^T
        f32x4 sw4 = *(const f32x4*)&sw[16 * wv + 4 * gq];
        f32x4 bias;
        bias[0] = hbc * sw4[0] + wbc; bias[1] = hbc * sw4[1] + wbc;
        bias[2] = hbc * sw4[2] + wbc; bias[3] = hbc * sw4[3] + wbc;

        bfrag pa0 = *(const bfrag*)&PT[(16 * wv + r) * STRB + gq * 8];
        bfrag pa1 = *(const bfrag*)&PT[(16 * wv + r) * STRB + 32 + gq * 8];
        f32x4 acc2[4] = {bias, bias, bias, bias};
        #pragma unroll
        for (int nt = 0; nt < 4; ++nt) {
            bfrag bh0 = *(const bfrag*)&Ah[(nt * 16 + r) * STRB + gq * 8];
            bfrag bh1 = *(const bfrag*)&Ah[(nt * 16 + r) * STRB + 32 + gq * 8];
            acc2[nt] = __builtin_amdgcn_mfma_f32_16x16x32_bf16(pa0, bh0, acc2[nt], 0, 0, 0);
            acc2[nt] = __builtin_amdgcn_mfma_f32_16x16x32_bf16(pa1, bh1, acc2[nt], 0, 0, 0);
        }

        // ---- store: lane holds Z[oh=16nt+r][ow=16wv+4gq+j], j contiguous -> dwordx4
        float* og = out + img0 + (size_t)i * imgStride;
        #pragma unroll
        for (int nt = 0; nt < 4; ++nt) {
            float4 v;
            v.x = acc2[nt][0]; v.y = acc2[nt][1];
            v.z = acc2[nt][2]; v.w = acc2[nt][3];
            *(float4*)&og[(size_t)(nt * 16 + r) * 64 + 16 * wv + 4 * gq] = v;
        }

        lds_barrier();   // all PT reads done -> PT writable next iteration
    }
}

extern "C" void kernel_launch(void* const* d_in, const int* in_sizes, int n_in,
                              void* d_out, int out_size, void* d_ws, size_t ws_size,
                              hipStream_t stream)
{
    const float* x   = (const float*)d_in[0];
    const float* hwt = (const float*)d_in[1];
    const float* wwt = (const float*)d_in[2];
    const float* hb  = (const float*)d_in[3];
    const float* wb  = (const float*)d_in[4];
    oversize_conv_mfma2<<<2048, 256, 0, stream>>>(x, hwt, wwt, hb, wb, (float*)d_out);
}